// Round 7
// baseline (477.337 us; speedup 1.0000x reference)
//
#include <hip/hip_runtime.h>
#include <hip/hip_bf16.h>
#include <stdint.h>

#define NTOK 16384
#define DDIM 4096
#define NEXP 128
#define BM 32
#define BK 64
#define NT (DDIM / BK)   // 64 k-tiles

typedef __attribute__((ext_vector_type(8))) short short8;   // 8 bf16 = 4 VGPRs (MFMA A/B frag)
typedef __attribute__((ext_vector_type(4))) float f32x4;    // MFMA C/D frag
typedef __attribute__((address_space(1))) const uint32_t gu32;
typedef __attribute__((address_space(3))) uint32_t lu32;

// async global->LDS, 16B per lane. Dest must be wave-uniform base + lane*16 (linear).
__device__ __forceinline__ void gload16(const void* g, void* l) {
    __builtin_amdgcn_global_load_lds((gu32*)g, (lu32*)l, 16, 0, 0);
}

// fp32 -> (hi, lo) bf16 pair, both RNE. f ~= hi + lo with |err| <~ 2^-17 |f|.
__device__ __forceinline__ void split_bf16(float f, uint32_t& h, uint32_t& l) {
    uint32_t u = __float_as_uint(f);
    h = (u + 0x7FFFu + ((u >> 16) & 1u)) >> 16;
    float r = f - __uint_as_float(h << 16);
    uint32_t v = __float_as_uint(r);
    l = (v + 0x7FFFu + ((v >> 16) & 1u)) >> 16;
}

// ---- kernel 1: split wg_weight [128][4096] fp32 -> w_hi, w_lo bf16 in ws ----
__global__ void prep_w(const float* __restrict__ w,
                       uint16_t* __restrict__ whi, uint16_t* __restrict__ wlo) {
    int i = (blockIdx.x * blockDim.x + threadIdx.x) * 4;
    float4 f = *(const float4*)(w + i);
    uint32_t h0, h1, h2, h3, l0, l1, l2, l3;
    split_bf16(f.x, h0, l0);
    split_bf16(f.y, h1, l1);
    split_bf16(f.z, h2, l2);
    split_bf16(f.w, h3, l3);
    uint2 hv = make_uint2(h0 | (h1 << 16), h2 | (h3 << 16));
    uint2 lv = make_uint2(l0 | (l1 << 16), l2 | (l3 << 16));
    *(uint2*)(whi + i) = hv;
    *(uint2*)(wlo + i) = lv;
}

// ---- kernel 2: logits = x @ w^T, split-bf16 3-product MFMA, counted-vmcnt dbuf ----
// (unchanged from R6 -- passed correctness, needs its timing)
// BM=32 tokens x 128 experts, 256 threads = 4 waves (wave = 32-expert column).
// 80 KB LDS -> 2 blocks/CU. T4 schedule: per iteration
//   load fa/fb (A, oldest) ; 8 wave-PRIVATE gload_lds (B rows this wave reads)
//   s_waitcnt vmcnt(10)     -> my B(t) landed (wave-private: no cross-wave B dep)
//   compute(t) ; writeA (compiler waits for fa/fb only)
//   s_waitcnt lgkmcnt(0) ; s_barrier   -> B(t+1) loads stay in flight ACROSS barrier
// LDS: linear [rows][64] bf16, XOR-swizzled 16B chunks: LDS(r,j)=global(r, j^(r&7))
// (R2-measured 0 bank conflicts; gload_lds-compatible: source pre-swizzled, dest linear).
__global__ __launch_bounds__(256) void gemm_logits(
    const float* __restrict__ x,
    const uint16_t* __restrict__ whi, const uint16_t* __restrict__ wlo,
    float* __restrict__ S)
{
    __shared__ uint16_t sAh[2][BM * BK], sAl[2][BM * BK];     //  8 KB +  8 KB
    __shared__ uint16_t sBh[2][NEXP * BK], sBl[2][NEXP * BK]; // 32 KB + 32 KB = 80 KB

    const int tid  = threadIdx.x;
    const int lane = tid & 63;
    const int wave = tid >> 6;     // expert column: experts wave*32 .. +31
    const int q = lane >> 4;       // quad id, k-group selector
    const int c = lane & 15;       // row (A) / col (B) within 16
    const int rxor = c & 7;        // all frag rows have row&7 == c&7
    const int m0 = blockIdx.x * BM;

    // A staging (block-wide, via regs+ds_write): thread t -> row t>>3, chunk t&7
    const int ar = tid >> 3, aj = tid & 7;
    const float* xp = x + (size_t)(m0 + ar) * DDIM + aj * 8;
    const int aoff = ar * BK + (aj ^ (ar & 7)) * 8;   // swizzled LDS elem offset

    // B staging (WAVE-PRIVATE): wave w stages rows w*32..w*32+31 (exactly what it
    // reads in compute). Per gld: 64 lanes = 8 rows x 8 chunks x 16B = 1 KB.
    const int brow = wave * 32 + (lane >> 3);                  // +i*8 per gld
    const int bjj  = (lane & 7) ^ ((lane >> 3) & 7);           // pre-swizzled src chunk
    const size_t bsrc = (size_t)brow * DDIM + bjj * 8;
    const int bdst = (wave * 32) * BK + lane * 8;              // +i*8*BK per gld

    f32x4 acc[2][2];
    #pragma unroll
    for (int mt = 0; mt < 2; ++mt)
        #pragma unroll
        for (int nt = 0; nt < 2; ++nt)
            acc[mt][nt] = (f32x4){0.f, 0.f, 0.f, 0.f};

    auto stageB = [&](int nxt, int kn) {
        #pragma unroll
        for (int i = 0; i < 4; ++i) {
            gload16(whi + bsrc + (size_t)(i * 8) * DDIM + kn, &sBh[nxt][bdst + i * 8 * BK]);
            gload16(wlo + bsrc + (size_t)(i * 8) * DDIM + kn, &sBl[nxt][bdst + i * 8 * BK]);
        }
    };

    auto writeA = [&](int nxt, float4 fa, float4 fb) {
        uint32_t h[8], l[8];
        split_bf16(fa.x, h[0], l[0]); split_bf16(fa.y, h[1], l[1]);
        split_bf16(fa.z, h[2], l[2]); split_bf16(fa.w, h[3], l[3]);
        split_bf16(fb.x, h[4], l[4]); split_bf16(fb.y, h[5], l[5]);
        split_bf16(fb.z, h[6], l[6]); split_bf16(fb.w, h[7], l[7]);
        uint4 hv = make_uint4(h[0] | (h[1] << 16), h[2] | (h[3] << 16),
                              h[4] | (h[5] << 16), h[6] | (h[7] << 16));
        uint4 lv = make_uint4(l[0] | (l[1] << 16), l[2] | (l[3] << 16),
                              l[4] | (l[5] << 16), l[6] | (l[7] << 16));
        *(uint4*)&sAh[nxt][aoff] = hv;
        *(uint4*)&sAl[nxt][aoff] = lv;
    };

    auto compute = [&](int cur) {
        #pragma unroll
        for (int ks = 0; ks < 2; ++ks) {
            const int off = (((ks << 2) | q) ^ rxor) << 3;  // swizzled chunk
            short8 ah[2], alo[2], bh[2], blo[2];
            #pragma unroll
            for (int mt = 0; mt < 2; ++mt) {
                const int ro = (mt * 16 + c) * BK + off;
                ah[mt]  = *(const short8*)&sAh[cur][ro];
                alo[mt] = *(const short8*)&sAl[cur][ro];
            }
            #pragma unroll
            for (int nt = 0; nt < 2; ++nt) {
                const int ro = (wave * 32 + nt * 16 + c) * BK + off;
                bh[nt]  = *(const short8*)&sBh[cur][ro];
                blo[nt] = *(const short8*)&sBl[cur][ro];
            }
            #pragma unroll
            for (int mt = 0; mt < 2; ++mt)
                #pragma unroll
                for (int nt = 0; nt < 2; ++nt) {
                    acc[mt][nt] = __builtin_amdgcn_mfma_f32_16x16x32_bf16(alo[mt], bh[nt],  acc[mt][nt], 0, 0, 0);
                    acc[mt][nt] = __builtin_amdgcn_mfma_f32_16x16x32_bf16(ah[mt],  blo[nt], acc[mt][nt], 0, 0, 0);
                    acc[mt][nt] = __builtin_amdgcn_mfma_f32_16x16x32_bf16(ah[mt],  bh[nt],  acc[mt][nt], 0, 0, 0);
                }
        }
    };

    // ---- prologue: stage tile 0, full drain (once only) ----
    {
        float4 fa = *(const float4*)(xp);
        float4 fb = *(const float4*)(xp + 4);
        asm volatile("" ::: "memory");
        stageB(0, 0);
        writeA(0, fa, fb);
        asm volatile("s_waitcnt vmcnt(0) lgkmcnt(0)" ::: "memory");
        __builtin_amdgcn_s_barrier();
    }

    // ---- main loop: counted vmcnt, barrier never drains VMEM ----
    #pragma unroll 2
    for (int t = 0; t < NT - 1; ++t) {
        const int cur = t & 1, nxt = cur ^ 1;
        const int kn = (t + 1) * BK;
        float4 fa = *(const float4*)(xp + kn);   // A loads FIRST (oldest in FIFO)
        float4 fb = *(const float4*)(xp + kn + 4);
        asm volatile("" ::: "memory");           // pin load order
        stageB(nxt, kn);                         // 8 glds (youngest)
        asm volatile("s_waitcnt vmcnt(10)" ::: "memory");  // my B(t) landed
        compute(cur);
        writeA(nxt, fa, fb);                     // compiler waits fa/fb only
        asm volatile("s_waitcnt lgkmcnt(0)" ::: "memory");
        __builtin_amdgcn_s_barrier();            // B(t+1) stays in flight
    }
    asm volatile("s_waitcnt vmcnt(0)" ::: "memory");  // last B tile landed
    compute((NT - 1) & 1);

    // ---- epilogue: C/D layout col=lane&15, row=(lane>>4)*4+reg (m89-verified) ----
    #pragma unroll
    for (int mt = 0; mt < 2; ++mt)
        #pragma unroll
        for (int nt = 0; nt < 2; ++nt) {
            const int e = wave * 32 + nt * 16 + c;
            #pragma unroll
            for (int r = 0; r < 4; ++r) {
                const int tok = m0 + mt * 16 + q * 4 + r;
                S[(size_t)tok * NEXP + e] = acc[mt][nt][r];
            }
        }
}

// ---- kernel 3: masked softmax + adaptive top-k, ballot-free fixed iterations ----
// 8-lane group per token (8 tokens/wave), 16 contiguous scores per lane.
// Extraction: k <= 33 provably (64 active: if cumexcl(34) < 0.5 then p(33) < 0.5/33
// and the remaining <=31 active values sum < 0.47 -> total < 1, contradiction).
// Fixed 33 iterations, k += (cum < 0.5): exclusive-cumsum count == reference.
// TIE FIX (R6 post-mortem): remove exactly ONE instance per iteration via a
// 64-bit argmax key (value_bits<<32 | unique_idx; monotone since scores > 0).
// Duplicated values then occupy one sorted position each, matching reference.
__global__ __launch_bounds__(256) void postproc(
    float* __restrict__ S, const float* __restrict__ mask,
    float* __restrict__ topk_out)
{
    const int lane = threadIdx.x & 63;
    const int wave = threadIdx.x >> 6;
    const int g  = lane >> 3;           // group (token) within wave
    const int gl = lane & 7;            // lane within group
    const int tok = blockIdx.x * 32 + wave * 8 + g;
    float* row = S + (size_t)tok * NEXP + gl * 16;
    const float* mrow = mask + gl * 16;

    float v[16];
    #pragma unroll
    for (int i = 0; i < 4; ++i)
        *(float4*)&v[i * 4] = *(const float4*)&row[i * 4];

    bool act[16];
    int cnt = 0;
    float mx = -3.0e38f;
    #pragma unroll
    for (int j = 0; j < 16; ++j) {
        act[j] = (mrow[j] != 0.f);
        cnt += act[j] ? 1 : 0;
        mx = fmaxf(mx, act[j] ? v[j] : -3.0e38f);
    }
    int active = cnt;
    #pragma unroll
    for (int off = 4; off; off >>= 1) active += __shfl_xor(active, off);
    #pragma unroll
    for (int off = 4; off; off >>= 1) mx = fmaxf(mx, __shfl_xor(mx, off));

    float sum = 0.f;
    #pragma unroll
    for (int j = 0; j < 16; ++j) {
        v[j] = act[j] ? __expf(v[j] - mx) : 0.f;
        sum += v[j];
    }
    #pragma unroll
    for (int off = 4; off; off >>= 1) sum += __shfl_xor(sum, off);

    const float inv = 1.0f / sum;
    #pragma unroll
    for (int j = 0; j < 16; ++j) v[j] = v[j] * inv + 1e-14f;
    #pragma unroll
    for (int i = 0; i < 4; ++i)
        *(float4*)&row[i * 4] = *(const float4*)&v[i * 4];

    // fixed-count extraction, single-instance removal via 64-bit key argmax.
    float cum = 0.f;
    int k = 0;
    const int base = gl * 16;
    for (int it = 0; it < 33; ++it) {
        float lm = v[0];
        int lj = 0;
        #pragma unroll
        for (int j = 1; j < 16; ++j) {
            const bool gt = v[j] > lm;
            lm = gt ? v[j] : lm;
            lj = gt ? j : lj;
        }
        unsigned long long key =
            ((unsigned long long)__float_as_uint(lm) << 32) | (unsigned)(base + lj);
        #pragma unroll
        for (int off = 4; off; off >>= 1) {
            unsigned long long o = __shfl_xor(key, off);
            key = (o > key) ? o : key;
        }
        const float mv = __uint_as_float((uint32_t)(key >> 32));
        const int widx = (int)(key & 127u);
        k += (cum < 0.5f) ? 1 : 0;
        cum += mv;
        #pragma unroll
        for (int j = 0; j < 16; ++j)
            v[j] = (widx == base + j) ? 0.f : v[j];   // clear exactly one instance
    }
    int topk = k < active ? k : active;
    if (gl == 0) topk_out[tok] = (float)topk;
}

extern "C" void kernel_launch(void* const* d_in, const int* in_sizes, int n_in,
                              void* d_out, int out_size, void* d_ws, size_t ws_size,
                              hipStream_t stream) {
    (void)in_sizes; (void)n_in; (void)out_size; (void)ws_size;
    const float* x    = (const float*)d_in[0];
    const float* w    = (const float*)d_in[1];
    const float* mask = (const float*)d_in[2];

    float* S    = (float*)d_out;                  // [16384,128] scores (also logit scratch)
    float* topk = S + (size_t)NTOK * NEXP;        // [16384] top_k as float

    uint16_t* whi = (uint16_t*)d_ws;              // [128,4096] bf16 hi
    uint16_t* wlo = whi + (size_t)NEXP * DDIM;    // [128,4096] bf16 lo

    hipLaunchKernelGGL(prep_w, dim3((NEXP * DDIM) / (256 * 4)), dim3(256), 0, stream,
                       w, whi, wlo);
    hipLaunchKernelGGL(gemm_logits, dim3(NTOK / BM), dim3(256), 0, stream,
                       x, whi, wlo, S);
    hipLaunchKernelGGL(postproc, dim3(NTOK / 32), dim3(256), 0, stream,
                       S, mask, topk);
}

// Round 8
// 474.720 us; speedup vs baseline: 1.0055x; 1.0055x over previous
//
#include <hip/hip_runtime.h>
#include <hip/hip_bf16.h>
#include <stdint.h>

#define NTOK 16384
#define DDIM 4096
#define NEXP 128
#define BM 32
#define BK 64
#define NT (DDIM / BK)   // 64 k-tiles

typedef __attribute__((ext_vector_type(8))) short short8;   // 8 bf16 = 4 VGPRs (MFMA A/B frag)
typedef __attribute__((ext_vector_type(4))) float f32x4;    // MFMA C/D frag

// fp32 -> (hi, lo) bf16 pair, both RNE. f ~= hi + lo with |err| <~ 2^-17 |f|.
__device__ __forceinline__ void split_bf16(float f, uint32_t& h, uint32_t& l) {
    uint32_t u = __float_as_uint(f);
    h = (u + 0x7FFFu + ((u >> 16) & 1u)) >> 16;
    float r = f - __uint_as_float(h << 16);
    uint32_t v = __float_as_uint(r);
    l = (v + 0x7FFFu + ((v >> 16) & 1u)) >> 16;
}

// ---- kernel 1: split wg_weight [128][4096] fp32 -> w_hi, w_lo bf16 in ws ----
__global__ void prep_w(const float* __restrict__ w,
                       uint16_t* __restrict__ whi, uint16_t* __restrict__ wlo) {
    int i = (blockIdx.x * blockDim.x + threadIdx.x) * 4;
    float4 f = *(const float4*)(w + i);
    uint32_t h0, h1, h2, h3, l0, l1, l2, l3;
    split_bf16(f.x, h0, l0);
    split_bf16(f.y, h1, l1);
    split_bf16(f.z, h2, l2);
    split_bf16(f.w, h3, l3);
    uint2 hv = make_uint2(h0 | (h1 << 16), h2 | (h3 << 16));
    uint2 lv = make_uint2(l0 | (l1 << 16), l2 | (l3 << 16));
    *(uint2*)(whi + i) = hv;
    *(uint2*)(wlo + i) = lv;
}

// ---- kernel 2: logits = x @ w^T, split-bf16 3-product MFMA, B-in-registers ----
// OCCUPANCY-FIRST redesign (R7 post-mortem: all 1-2 blk/CU schedules latency-
// bound at 145-271us regardless of structure; both pipes <8% busy).
//   * B never touches LDS: each wave loads its fragment rows straight from
//     whi/wlo (L2-resident, 2 MB) into regs. Per load instruction: 16 rows x
//     64 contiguous bytes = clean 64B L2 lines, zero over-fetch, no barrier.
//   * LDS = double-buffered A only (16 KB), reg-staged (load/split/ds_write),
//     XOR-swizzled 16B chunks (R2-measured 0 conflicts).
//   * One __syncthreads per iter, NO inline asm -- compiler schedules waits.
//   * __launch_bounds__(256,4): VGPR<=128 -> 4 blocks/CU = 16 waves/CU of TLP.
__global__ __launch_bounds__(256, 4) void gemm_logits(
    const float* __restrict__ x,
    const uint16_t* __restrict__ whi, const uint16_t* __restrict__ wlo,
    float* __restrict__ S)
{
    __shared__ uint16_t sAh[2][BM * BK], sAl[2][BM * BK];   // 8 KB + 8 KB

    const int tid  = threadIdx.x;
    const int lane = tid & 63;
    const int wave = tid >> 6;     // expert column: experts wave*32 .. +31
    const int q = lane >> 4;       // quad id, k-group selector
    const int c = lane & 15;       // row (A) / col (B) within 16
    const int rxor = c & 7;        // all A frag rows have row&7 == c&7
    const int m0 = blockIdx.x * BM;

    // A staging: thread t -> row t>>3, chunk t&7 (swizzled LDS dest)
    const int ar = tid >> 3, aj = tid & 7;
    const float* xp = x + (size_t)(m0 + ar) * DDIM + aj * 8;
    const int aoff = ar * BK + (aj ^ (ar & 7)) * 8;

    // B fragment bases: this wave+lane reads rows wave*32 + nt*16 + c,
    // k-offset k0 + ks*32 + q*8 (8 bf16 = 16B per frag).
    const size_t brow = (size_t)(wave * 32 + c) * DDIM + q * 8;
    const uint16_t* bh_p = whi + brow;
    const uint16_t* bl_p = wlo + brow;

    f32x4 acc[2][2];
    #pragma unroll
    for (int mt = 0; mt < 2; ++mt)
        #pragma unroll
        for (int nt = 0; nt < 2; ++nt)
            acc[mt][nt] = (f32x4){0.f, 0.f, 0.f, 0.f};

    auto writeA = [&](int nxt, float4 fa, float4 fb) {
        uint32_t h[8], l[8];
        split_bf16(fa.x, h[0], l[0]); split_bf16(fa.y, h[1], l[1]);
        split_bf16(fa.z, h[2], l[2]); split_bf16(fa.w, h[3], l[3]);
        split_bf16(fb.x, h[4], l[4]); split_bf16(fb.y, h[5], l[5]);
        split_bf16(fb.z, h[6], l[6]); split_bf16(fb.w, h[7], l[7]);
        uint4 hv = make_uint4(h[0] | (h[1] << 16), h[2] | (h[3] << 16),
                              h[4] | (h[5] << 16), h[6] | (h[7] << 16));
        uint4 lv = make_uint4(l[0] | (l[1] << 16), l[2] | (l[3] << 16),
                              l[4] | (l[5] << 16), l[6] | (l[7] << 16));
        *(uint4*)&sAh[nxt][aoff] = hv;
        *(uint4*)&sAl[nxt][aoff] = lv;
    };

    // ---- prologue: stage A tile 0 ----
    {
        float4 fa = *(const float4*)(xp);
        float4 fb = *(const float4*)(xp + 4);
        writeA(0, fa, fb);
        __syncthreads();
    }

    // ---- main loop: 1 barrier/iter, B straight to regs, A double-buffered ----
    #pragma unroll 2
    for (int t = 0; t < NT; ++t) {
        const int cur = t & 1;
        const int k0 = t * BK;

        // B fragments for THIS tile (issued first = oldest in FIFO)
        short8 bh[2][2], bl[2][2];     // [nt][ks]
        #pragma unroll
        for (int nt = 0; nt < 2; ++nt)
            #pragma unroll
            for (int ks = 0; ks < 2; ++ks) {
                const size_t o = (size_t)(nt * 16) * DDIM + k0 + ks * 32;
                bh[nt][ks] = *(const short8*)(bh_p + o);
                bl[nt][ks] = *(const short8*)(bl_p + o);
            }

        // A loads for NEXT tile (consumed by writeA after compute)
        float4 fa, fb;
        if (t + 1 < NT) {
            fa = *(const float4*)(xp + k0 + BK);
            fb = *(const float4*)(xp + k0 + BK + 4);
        }

        // compute: A frags from LDS, B frags from regs
        #pragma unroll
        for (int ks = 0; ks < 2; ++ks) {
            const int off = (((ks << 2) | q) ^ rxor) << 3;  // swizzled A chunk
            short8 ah[2], alo[2];
            #pragma unroll
            for (int mt = 0; mt < 2; ++mt) {
                const int ro = (mt * 16 + c) * BK + off;
                ah[mt]  = *(const short8*)&sAh[cur][ro];
                alo[mt] = *(const short8*)&sAl[cur][ro];
            }
            #pragma unroll
            for (int mt = 0; mt < 2; ++mt)
                #pragma unroll
                for (int nt = 0; nt < 2; ++nt) {
                    acc[mt][nt] = __builtin_amdgcn_mfma_f32_16x16x32_bf16(alo[mt], bh[nt][ks], acc[mt][nt], 0, 0, 0);
                    acc[mt][nt] = __builtin_amdgcn_mfma_f32_16x16x32_bf16(ah[mt],  bl[nt][ks], acc[mt][nt], 0, 0, 0);
                    acc[mt][nt] = __builtin_amdgcn_mfma_f32_16x16x32_bf16(ah[mt],  bh[nt][ks], acc[mt][nt], 0, 0, 0);
                }
        }

        if (t + 1 < NT) {
            writeA(cur ^ 1, fa, fb);
            __syncthreads();
        }
    }

    // ---- epilogue: C/D layout col=lane&15, row=(lane>>4)*4+reg (m89-verified) ----
    #pragma unroll
    for (int mt = 0; mt < 2; ++mt)
        #pragma unroll
        for (int nt = 0; nt < 2; ++nt) {
            const int e = wave * 32 + nt * 16 + c;
            #pragma unroll
            for (int r = 0; r < 4; ++r) {
                const int tok = m0 + mt * 16 + q * 4 + r;
                S[(size_t)tok * NEXP + e] = acc[mt][nt][r];
            }
        }
}

// ---- kernel 3: masked softmax + adaptive top-k, ballot-free fixed iterations ----
// (unchanged from R7 -- passed; ledger says ~38us)
// 8-lane group per token (8 tokens/wave), 16 contiguous scores per lane.
// k <= 33 provably; fixed 33 iterations, k += (cum < 0.5) exclusive-cumsum count.
// Single-instance tie removal via 64-bit argmax key (value_bits<<32 | idx).
__global__ __launch_bounds__(256) void postproc(
    float* __restrict__ S, const float* __restrict__ mask,
    float* __restrict__ topk_out)
{
    const int lane = threadIdx.x & 63;
    const int wave = threadIdx.x >> 6;
    const int g  = lane >> 3;           // group (token) within wave
    const int gl = lane & 7;            // lane within group
    const int tok = blockIdx.x * 32 + wave * 8 + g;
    float* row = S + (size_t)tok * NEXP + gl * 16;
    const float* mrow = mask + gl * 16;

    float v[16];
    #pragma unroll
    for (int i = 0; i < 4; ++i)
        *(float4*)&v[i * 4] = *(const float4*)&row[i * 4];

    bool act[16];
    int cnt = 0;
    float mx = -3.0e38f;
    #pragma unroll
    for (int j = 0; j < 16; ++j) {
        act[j] = (mrow[j] != 0.f);
        cnt += act[j] ? 1 : 0;
        mx = fmaxf(mx, act[j] ? v[j] : -3.0e38f);
    }
    int active = cnt;
    #pragma unroll
    for (int off = 4; off; off >>= 1) active += __shfl_xor(active, off);
    #pragma unroll
    for (int off = 4; off; off >>= 1) mx = fmaxf(mx, __shfl_xor(mx, off));

    float sum = 0.f;
    #pragma unroll
    for (int j = 0; j < 16; ++j) {
        v[j] = act[j] ? __expf(v[j] - mx) : 0.f;
        sum += v[j];
    }
    #pragma unroll
    for (int off = 4; off; off >>= 1) sum += __shfl_xor(sum, off);

    const float inv = 1.0f / sum;
    #pragma unroll
    for (int j = 0; j < 16; ++j) v[j] = v[j] * inv + 1e-14f;
    #pragma unroll
    for (int i = 0; i < 4; ++i)
        *(float4*)&row[i * 4] = *(const float4*)&v[i * 4];

    // fixed-count extraction, single-instance removal via 64-bit key argmax.
    float cum = 0.f;
    int k = 0;
    const int base = gl * 16;
    for (int it = 0; it < 33; ++it) {
        float lm = v[0];
        int lj = 0;
        #pragma unroll
        for (int j = 1; j < 16; ++j) {
            const bool gt = v[j] > lm;
            lm = gt ? v[j] : lm;
            lj = gt ? j : lj;
        }
        unsigned long long key =
            ((unsigned long long)__float_as_uint(lm) << 32) | (unsigned)(base + lj);
        #pragma unroll
        for (int off = 4; off; off >>= 1) {
            unsigned long long o = __shfl_xor(key, off);
            key = (o > key) ? o : key;
        }
        const float mv = __uint_as_float((uint32_t)(key >> 32));
        const int widx = (int)(key & 127u);
        k += (cum < 0.5f) ? 1 : 0;
        cum += mv;
        #pragma unroll
        for (int j = 0; j < 16; ++j)
            v[j] = (widx == base + j) ? 0.f : v[j];   // clear exactly one instance
    }
    int topk = k < active ? k : active;
    if (gl == 0) topk_out[tok] = (float)topk;
}

extern "C" void kernel_launch(void* const* d_in, const int* in_sizes, int n_in,
                              void* d_out, int out_size, void* d_ws, size_t ws_size,
                              hipStream_t stream) {
    (void)in_sizes; (void)n_in; (void)out_size; (void)ws_size;
    const float* x    = (const float*)d_in[0];
    const float* w    = (const float*)d_in[1];
    const float* mask = (const float*)d_in[2];

    float* S    = (float*)d_out;                  // [16384,128] scores (also logit scratch)
    float* topk = S + (size_t)NTOK * NEXP;        // [16384] top_k as float

    uint16_t* whi = (uint16_t*)d_ws;              // [128,4096] bf16 hi
    uint16_t* wlo = whi + (size_t)NEXP * DDIM;    // [128,4096] bf16 lo

    hipLaunchKernelGGL(prep_w, dim3((NEXP * DDIM) / (256 * 4)), dim3(256), 0, stream,
                       w, whi, wlo);
    hipLaunchKernelGGL(gemm_logits, dim3(NTOK / BM), dim3(256), 0, stream,
                       x, whi, wlo, S);
    hipLaunchKernelGGL(postproc, dim3(NTOK / 32), dim3(256), 0, stream,
                       S, mask, topk);
}